// Round 5
// baseline (1443.108 us; speedup 1.0000x reference)
//
#include <hip/hip_runtime.h>
#include <hip/hip_bf16.h>
#include <math.h>

// Suffix-max scan along H (reverse), NCHW: x[8,128,256,256] f32.
// out[n,c,h,w] = max_{j>=h} x[n,c,j,w].
//
// R5 = DIAGNOSTIC round. R0/R3/R4 all ~430us despite opposite designs;
// rocprof top-5 shows only 165us 1GiB harness fills => our kernel is
// <163us and dur_us carries ~295us of harness reset overhead. To get the
// kernel's own counters into the top-5 and solve K exactly, run the R4
// body REPS=4 times (idempotent). Opaque rep_off (asm "+v") defeats
// cross-rep CSE of the restrict-invariant loads (rule #17).
// Solve: K = (dur_us - 424)/3. Kernel dispatch shows FETCH/WRITE/VALU.

#define H 256
#define W 256
#define CH 64   // chunk height (H / 4)
#define REPS 4

__global__ __launch_bounds__(256) void VerticalLinePool_kernel(
    const float* __restrict__ x, float* __restrict__ out) {
    const int tid = threadIdx.x;
    const int c  = tid >> 6;             // chunk index 0..3 (wave-uniform)
    const int wl = tid & 63;             // lane -> column within quarter
    const int q    = blockIdx.x & 3;     // w-quarter 0..3
    const int slab = blockIdx.x >> 2;    // (n,c) slab 0..1023

    const size_t col = (size_t)slab * (H * W) + (size_t)q * 64 + wl;
    const float* __restrict__ xp = x + col;
    float* __restrict__ op = out + col;

    const int h0 = c * CH;

    __shared__ float tot[4][64];

    int rep_off = 0;   // always 0, but opaque to the compiler
    for (int rep = 0; rep < REPS; ++rep) {
        asm volatile("" : "+v"(rep_off));            // launder: loads can't CSE across reps
        const float* __restrict__ xp2 = xp + rep_off;

        // Phase 1: pure-load suffix scan of this chunk, kept in registers.
        float s[CH];
        float run = -INFINITY;
#pragma unroll
        for (int i = CH - 1; i >= 0; --i) {
            float v = __builtin_nontemporal_load(&xp2[(size_t)(h0 + i) * W]);
            run = fmaxf(run, v);
            s[i] = run;
        }

        // Share chunk totals; chunk c needs max over chunks c+1..3.
        tot[c][wl] = run;
        __syncthreads();

        float M = -INFINITY;             // branches wave-uniform (c = wave id)
        if (c < 3) M = tot[c + 1][wl];
        if (c < 2) M = fmaxf(M, tot[c + 2][wl]);
        if (c < 1) M = fmaxf(M, tot[c + 3][wl]);

        // Phase 2: pure-store pass (exact addresses -> idempotent & correct).
#pragma unroll
        for (int i = 0; i < CH; ++i) {
            __builtin_nontemporal_store(fmaxf(s[i], M), &op[(size_t)(h0 + i) * W]);
        }
        __syncthreads();                 // tot[] reused next rep
    }
}

extern "C" void kernel_launch(void* const* d_in, const int* in_sizes, int n_in,
                              void* d_out, int out_size, void* d_ws, size_t ws_size,
                              hipStream_t stream) {
    const float* x = (const float*)d_in[0];
    float* out = (float*)d_out;
    const int slabs = in_sizes[0] / (H * W);   // 8*128 = 1024
    VerticalLinePool_kernel<<<slabs * 4, 256, 0, stream>>>(x, out);
}

// Round 6
// 439.056 us; speedup vs baseline: 3.2868x; 3.2868x over previous
//
#include <hip/hip_runtime.h>
#include <hip/hip_bf16.h>
#include <math.h>

// Suffix-max scan along H (reverse), NCHW: x[8,128,256,256] f32.
// out[n,c,h,w] = max_{j>=h} x[n,c,j,w].
//
// R6: register double-buffered tile pipeline.
// Calibration (R5): dur_us carries ~316us fixed harness overhead; R4's
// kernel was ~114us (~4.5 TB/s) vs fill kernels at 6.5 TB/s. Theory: the
// single-buffered load->wait->store loop leaves the read pipe empty while
// consuming; fix = double-buffer 16-row tiles in VGPRs so the next tile's
// 16x1KiB loads are always in flight (in-order vmcnt: waiting on tile k
// keeps tile k+1's loads outstanding).
//
// Wave owns one slab (n,c); lane owns f32x4 -> every VMEM op is a full
// 1 KiB row. Tiles processed descending-h (carry acc); loads/stores
// ascending within tile. Plain loads/stores (match the 6.5 TB/s fill).
// No LDS, no __syncthreads. ~150 VGPR, 4 waves/CU launched.

#define H 256
#define W 256
#define T 16          // tile rows
#define RS (W / 4)    // row stride in f32x4 units = 64

typedef float f32x4 __attribute__((ext_vector_type(4)));

__device__ __forceinline__ f32x4 max4(f32x4 a, f32x4 b) {
    f32x4 r;
    r.x = fmaxf(a.x, b.x);
    r.y = fmaxf(a.y, b.y);
    r.z = fmaxf(a.z, b.z);
    r.w = fmaxf(a.w, b.w);
    return r;
}

__global__ __launch_bounds__(256) void VerticalLinePool_kernel(
    const float* __restrict__ x, float* __restrict__ out) {
    const int lane = threadIdx.x & 63;          // f32x4 group within row
    const int wv   = threadIdx.x >> 6;          // wave -> slab within block
    const int slab = blockIdx.x * 4 + wv;       // 0..1023

    const size_t base = (size_t)slab * (H * W) + (size_t)lane * 4;
    const f32x4* __restrict__ xp = (const f32x4*)(x + base);
    f32x4* __restrict__ op = (f32x4*)(out + base);

    f32x4 A[T], B[T];
    f32x4 acc = (f32x4)(-INFINITY);

#define LOAD(buf, t)                                              \
    _Pragma("unroll")                                             \
    for (int i = 0; i < T; ++i)                                   \
        buf[i] = xp[(size_t)((t) * T + i) * RS];

#define CONSUME(buf, t)                                           \
    _Pragma("unroll")                                             \
    for (int i = T - 1; i >= 0; --i) {                            \
        acc = max4(acc, buf[i]);                                  \
        buf[i] = acc;                                             \
    }                                                             \
    _Pragma("unroll")                                             \
    for (int i = 0; i < T; ++i)                                   \
        op[(size_t)((t) * T + i) * RS] = buf[i];

    // 16 tiles, descending h; software-pipelined in register pairs.
    LOAD(A, 15);
#pragma unroll
    for (int t = 15; t >= 1; t -= 2) {
        LOAD(B, t - 1);      // next tile's loads in flight...
        CONSUME(A, t);       // ...while consuming current tile
        if (t - 2 >= 0) { LOAD(A, t - 2); }
        CONSUME(B, t - 1);
    }

#undef LOAD
#undef CONSUME
}

extern "C" void kernel_launch(void* const* d_in, const int* in_sizes, int n_in,
                              void* d_out, int out_size, void* d_ws, size_t ws_size,
                              hipStream_t stream) {
    const float* x = (const float*)d_in[0];
    float* out = (float*)d_out;
    const int slabs = in_sizes[0] / (H * W);    // 8*128 = 1024
    VerticalLinePool_kernel<<<slabs / 4, 256, 0, stream>>>(x, out);
}

// Round 7
// 436.225 us; speedup vs baseline: 3.3082x; 1.0065x over previous
//
#include <hip/hip_runtime.h>
#include <hip/hip_bf16.h>
#include <math.h>

// Suffix-max scan along H (reverse), NCHW: x[8,128,256,256] f32.
// out[n,c,h,w] = max_{j>=h} x[n,c,j,w].
//
// R7: max-occupancy 2-phase chunked scan.
// Calibration: dur_us = kernel + ~316us harness resets. R0/R3/R4/R6
// (4.2-4.7 TB/s kernel-rate) were insensitive to granularity/NT/dbuf.
// Theory: VMEM-issue duty cycle ~33% x ~3.8 waves/SIMD (R4) barely covers
// the vmcnt stall; raise occupancy to the 8-waves/SIMD hardware max.
// CH=16 rows/thread -> s[16] (~40 VGPR, <=64 enforced); 1024-thread
// blocks = 16 chunks x 64 columns (W-quarter); 2 blocks/CU = 32 waves/CU.
// Phase 1 pure loads (suffix-scan chunk into regs), LDS-share 16 chunk
// totals, phase 2 pure stores. Traffic stays 256 MiB + 256 MiB.

#define H 256
#define W 256
#define CH 16    // rows per thread
#define NC 16    // chunks per slab (H/CH)

__global__ __launch_bounds__(1024, 8) void VerticalLinePool_kernel(
    const float* __restrict__ x, float* __restrict__ out) {
    const int tid = threadIdx.x;
    const int c  = tid >> 6;             // chunk 0..15 (wave-uniform)
    const int wl = tid & 63;             // column within quarter
    const int q    = blockIdx.x & 3;     // w-quarter
    const int slab = blockIdx.x >> 2;    // (n,c) slab 0..1023

    const size_t col = (size_t)slab * (H * W) + (size_t)q * 64 + wl;
    const float* __restrict__ xp = x + col;
    float* __restrict__ op = out + col;

    const int h0 = c * CH;

    // Phase 1: pure-load suffix scan of this chunk, kept in registers.
    float s[CH];
    float run = -INFINITY;
#pragma unroll
    for (int i = CH - 1; i >= 0; --i) {
        float v = xp[(size_t)(h0 + i) * W];
        run = fmaxf(run, v);
        s[i] = run;
    }

    // Share chunk totals; chunk c needs max over chunks c+1..15.
    __shared__ float tot[NC][64];
    tot[c][wl] = run;
    __syncthreads();

    float M = -INFINITY;                 // loop count wave-uniform (c = wave id)
    for (int k = c + 1; k < NC; ++k)
        M = fmaxf(M, tot[k][wl]);

    // Phase 2: pure-store pass.
#pragma unroll
    for (int i = 0; i < CH; ++i) {
        op[(size_t)(h0 + i) * W] = fmaxf(s[i], M);
    }
}

extern "C" void kernel_launch(void* const* d_in, const int* in_sizes, int n_in,
                              void* d_out, int out_size, void* d_ws, size_t ws_size,
                              hipStream_t stream) {
    const float* x = (const float*)d_in[0];
    float* out = (float*)d_out;
    const int slabs = in_sizes[0] / (H * W);   // 8*128 = 1024
    VerticalLinePool_kernel<<<slabs * 4, 1024, 0, stream>>>(x, out);
}